// Round 12
// baseline (230.722 us; speedup 1.0000x reference)
//
#include <hip/hip_runtime.h>

#define BLOCK 256
// R11 (resubmit; previous round was an infra failure, no data): j-packed
// VOP3P at ONE row per thread.
// Ledger: stall tracks WAVE COUNT, not weight traffic -- R0 (31250 waves,
// occ 65%): 21us stall; R3/R10 (15625 waves, occ 50%): 29-30us, with weight
// dwords 819 vs 1681 making no difference at fixed waves (R10 falsified the
// traffic theory). All variants have VGPR<=64 (8 waves/SIMD allowed); the
// pair-packed ones just have half the waves to hide s_load/vmem latency.
// So: keep packed math (v_pk_fma halves the stream vs R0's scalar 900 inst)
// but pack over OUTPUT PAIRS (j,j+1) of a single row -> 7813 blocks / 31250
// waves (R0-level TLP). Weight pair {w[i][j],w[i][j+1]} is contiguous u64 ->
// s_load_dwordx2 SGPR pair (legal VOP3P src; R7: a lone 32-bit SGPR is not).
// Input broadcast by the INSTRUCTION: op_sel routes lo/hi of a legal 64-bit
// pair to both halves (HW-verified correct in R10):
//   fmaL: op_sel:[0,0,0] op_sel_hi:[0,1,1]   (src0.lo -> both halves)
//   fmaH: op_sel:[1,0,0] op_sel_hi:[1,1,1]   (src0.hi -> both halves)
// Layer outputs ARE j-pairs consumed as lo/hi by the next layer; the 11 raw
// features pack into 6 natural pairs. ~470 inst/row: 382 pk_fma + 12 scalar
// head fma + ~40 bias init + ~20 pk_max. Live set ~55 VGPR -> 8 waves/SIMD.
// No dup table, no prep kernel. Locals <=16-elem constant-indexed (R1/R4).

typedef float v2f __attribute__((ext_vector_type(2)));
typedef unsigned long long u64;

struct WPtrs {
    const float* w[19];
    const float* b[19];
};

enum LId {FU1,FU2,KU1,KU2,HU1,HU2,MD1,MD2,MD3,HD1,HD2,KD1,KD2,HA1,HA2,KA1,KA2,FA1,FA2};

// acc.{lo,hi} += s.lo * w.{lo,hi}
__device__ __forceinline__ void fmaL(v2f& acc, const v2f s, const u64 w) {
    asm("v_pk_fma_f32 %0, %1, %2, %0 op_sel:[0,0,0] op_sel_hi:[0,1,1]"
        : "+v"(acc) : "v"(s), "s"(w));
}
// acc.{lo,hi} += s.hi * w.{lo,hi}
__device__ __forceinline__ void fmaH(v2f& acc, const v2f s, const u64 w) {
    asm("v_pk_fma_f32 %0, %1, %2, %0 op_sel:[1,0,0] op_sel_hi:[1,1,1]"
        : "+v"(acc) : "v"(s), "s"(w));
}
__device__ __forceinline__ v2f pkmax0(const v2f a) {
    const v2f z = {0.0f, 0.0f};
    return __builtin_elementwise_max(a, z);
}
__device__ __forceinline__ v2f bias2(const float* b, int jp) {
    return *reinterpret_cast<const v2f*>(b + 2*jp);   // 8B-aligned (jp even elems)
}

__global__ __launch_bounds__(BLOCK) void pnet_kernel(
    const float* __restrict__ x, float* __restrict__ out, int B, WPtrs P) {
    const long long row = (long long)blockIdx.x * BLOCK + threadIdx.x;
    if (row >= B) return;

    // ---- load 11 features, pack into natural pairs ----
    const float* pr = x + row * 11;
    float xs[11];
#pragma unroll
    for (int c = 0; c < 11; ++c) xs[c] = pr[c];
    const v2f xp01 = {xs[0], xs[1]};
    const v2f xp23 = {xs[2], xs[3]};   // h = lo, k = hi
    const v2f xp45 = {xs[4], xs[5]};   // f = lo
    const v2f xp67 = {xs[6], xs[7]};
    const v2f xp89 = {xs[8], xs[9]};   // hd = lo, kd = hi
    const v2f xpA  = {xs[10], xs[10]}; // fd = lo

    // ---- fu1: [f, fd] -> 2 (1 jp) ----
    v2f fu1p;
    {
        const u64* wp = reinterpret_cast<const u64*>(P.w[FU1]);
        v2f a = bias2(P.b[FU1], 0);
        fmaL(a, xp45, wp[0]);          // f   * w[0][0..1]
        fmaL(a, xpA,  wp[1]);          // fd  * w[1][0..1]
        fu1p = pkmax0(a);
    }
    // ---- fu2: 2 -> 2 ----
    v2f fup;
    {
        const u64* wp = reinterpret_cast<const u64*>(P.w[FU2]);
        v2f a = bias2(P.b[FU2], 0);
        fmaL(a, fu1p, wp[0]);
        fmaH(a, fu1p, wp[1]);
        fup = pkmax0(a);
    }

    // ---- ku1: [k, kd, f_up(2)] -> 4 (2 jp), idx = i*2+jp ----
    v2f ku1p[2];
    {
        const u64* wp = reinterpret_cast<const u64*>(P.w[KU1]);
#pragma unroll
        for (int jp = 0; jp < 2; ++jp) {
            v2f a = bias2(P.b[KU1], jp);
            fmaH(a, xp23, wp[0*2+jp]);     // k
            fmaH(a, xp89, wp[1*2+jp]);     // kd
            fmaL(a, fup,  wp[2*2+jp]);
            fmaH(a, fup,  wp[3*2+jp]);
            ku1p[jp] = pkmax0(a);
        }
    }
    // ---- ku2: 4 -> 4 ----
    v2f kup[2];
    {
        const u64* wp = reinterpret_cast<const u64*>(P.w[KU2]);
#pragma unroll
        for (int jp = 0; jp < 2; ++jp) {
            v2f a = bias2(P.b[KU2], jp);
            fmaL(a, ku1p[0], wp[0*2+jp]);
            fmaH(a, ku1p[0], wp[1*2+jp]);
            fmaL(a, ku1p[1], wp[2*2+jp]);
            fmaH(a, ku1p[1], wp[3*2+jp]);
            kup[jp] = pkmax0(a);
        }
    }

    // ---- hu1: [h, hd, k_up(4)] -> 6 (3 jp), idx = i*3+jp ----
    v2f hu1p[3];
    {
        const u64* wp = reinterpret_cast<const u64*>(P.w[HU1]);
#pragma unroll
        for (int jp = 0; jp < 3; ++jp) {
            v2f a = bias2(P.b[HU1], jp);
            fmaL(a, xp23,   wp[0*3+jp]);   // h
            fmaL(a, xp89,   wp[1*3+jp]);   // hd
            fmaL(a, kup[0], wp[2*3+jp]);
            fmaH(a, kup[0], wp[3*3+jp]);
            fmaL(a, kup[1], wp[4*3+jp]);
            fmaH(a, kup[1], wp[5*3+jp]);
            hu1p[jp] = pkmax0(a);
        }
    }
    // ---- hu2: 6 -> 6 ----
    v2f hup[3];
    {
        const u64* wp = reinterpret_cast<const u64*>(P.w[HU2]);
#pragma unroll
        for (int jp = 0; jp < 3; ++jp) {
            v2f a = bias2(P.b[HU2], jp);
            fmaL(a, hu1p[0], wp[0*3+jp]);
            fmaH(a, hu1p[0], wp[1*3+jp]);
            fmaL(a, hu1p[1], wp[2*3+jp]);
            fmaH(a, hu1p[1], wp[3*3+jp]);
            fmaL(a, hu1p[2], wp[4*3+jp]);
            fmaH(a, hu1p[2], wp[5*3+jp]);
            hup[jp] = pkmax0(a);
        }
    }

    // ---- md1: [x0,x1,x5,x6,x7, h_up(6)] -> 16 (8 jp), idx = i*8+jp ----
    v2f m1[8];
    {
        const u64* wp = reinterpret_cast<const u64*>(P.w[MD1]);
#pragma unroll
        for (int jp = 0; jp < 8; ++jp) {
            v2f a = bias2(P.b[MD1], jp);
            fmaL(a, xp01,   wp[0*8+jp]);   // x0
            fmaH(a, xp01,   wp[1*8+jp]);   // x1
            fmaH(a, xp45,   wp[2*8+jp]);   // x5
            fmaL(a, xp67,   wp[3*8+jp]);   // x6
            fmaH(a, xp67,   wp[4*8+jp]);   // x7
            fmaL(a, hup[0], wp[5*8+jp]);
            fmaH(a, hup[0], wp[6*8+jp]);
            fmaL(a, hup[1], wp[7*8+jp]);
            fmaH(a, hup[1], wp[8*8+jp]);
            fmaL(a, hup[2], wp[9*8+jp]);
            fmaH(a, hup[2], wp[10*8+jp]);
            m1[jp] = pkmax0(a);
        }
    }
    // ---- md2: 16 -> 16 (8 jp) ----
    v2f m2[8];
    {
        const u64* wp = reinterpret_cast<const u64*>(P.w[MD2]);
#pragma unroll
        for (int jp = 0; jp < 8; ++jp) {
            v2f a = bias2(P.b[MD2], jp);
#pragma unroll
            for (int p = 0; p < 8; ++p) {
                fmaL(a, m1[p], wp[(2*p)  *8+jp]);
                fmaH(a, m1[p], wp[(2*p+1)*8+jp]);
            }
            m2[jp] = pkmax0(a);
        }
    }
    // ---- md3: 16 -> 6 (3 jp), idx = i*3+jp ----
    v2f m3[3];
    {
        const u64* wp = reinterpret_cast<const u64*>(P.w[MD3]);
#pragma unroll
        for (int jp = 0; jp < 3; ++jp) {
            v2f a = bias2(P.b[MD3], jp);
#pragma unroll
            for (int p = 0; p < 8; ++p) {
                fmaL(a, m2[p], wp[(2*p)  *3+jp]);
                fmaH(a, m2[p], wp[(2*p+1)*3+jp]);
            }
            m3[jp] = pkmax0(a);
        }
    }

    // ---- hd1: 6 -> 4 (2 jp), idx = i*2+jp ----
    v2f d1[2];
    {
        const u64* wp = reinterpret_cast<const u64*>(P.w[HD1]);
#pragma unroll
        for (int jp = 0; jp < 2; ++jp) {
            v2f a = bias2(P.b[HD1], jp);
            fmaL(a, m3[0], wp[0*2+jp]);
            fmaH(a, m3[0], wp[1*2+jp]);
            fmaL(a, m3[1], wp[2*2+jp]);
            fmaH(a, m3[1], wp[3*2+jp]);
            fmaL(a, m3[2], wp[4*2+jp]);
            fmaH(a, m3[2], wp[5*2+jp]);
            d1[jp] = pkmax0(a);
        }
    }
    // ---- hd2: 4 -> 4 (2 jp) ----
    v2f d2[2];
    {
        const u64* wp = reinterpret_cast<const u64*>(P.w[HD2]);
#pragma unroll
        for (int jp = 0; jp < 2; ++jp) {
            v2f a = bias2(P.b[HD2], jp);
            fmaL(a, d1[0], wp[0*2+jp]);
            fmaH(a, d1[0], wp[1*2+jp]);
            fmaL(a, d1[1], wp[2*2+jp]);
            fmaH(a, d1[1], wp[3*2+jp]);
            d2[jp] = pkmax0(a);
        }
    }

    // ---- kd1: 4 -> 2 (1 jp) ----
    v2f e1;
    {
        const u64* wp = reinterpret_cast<const u64*>(P.w[KD1]);
        v2f a = bias2(P.b[KD1], 0);
        fmaL(a, d2[0], wp[0]);
        fmaH(a, d2[0], wp[1]);
        fmaL(a, d2[1], wp[2]);
        fmaH(a, d2[1], wp[3]);
        e1 = pkmax0(a);
    }
    // ---- kd2: 2 -> 2 ----
    v2f e2;
    {
        const u64* wp = reinterpret_cast<const u64*>(P.w[KD2]);
        v2f a = bias2(P.b[KD2], 0);
        fmaL(a, e1, wp[0]);
        fmaH(a, e1, wp[1]);
        e2 = pkmax0(a);
    }

    // ---- ha1: [h, hd, m_down(6)] -> 4 (2 jp), idx = i*2+jp ----
    v2f g[2];
    {
        const u64* wp = reinterpret_cast<const u64*>(P.w[HA1]);
#pragma unroll
        for (int jp = 0; jp < 2; ++jp) {
            v2f a = bias2(P.b[HA1], jp);
            fmaL(a, xp23,  wp[0*2+jp]);    // h
            fmaL(a, xp89,  wp[1*2+jp]);    // hd
            fmaL(a, m3[0], wp[2*2+jp]);
            fmaH(a, m3[0], wp[3*2+jp]);
            fmaL(a, m3[1], wp[4*2+jp]);
            fmaH(a, m3[1], wp[5*2+jp]);
            fmaL(a, m3[2], wp[6*2+jp]);
            fmaH(a, m3[2], wp[7*2+jp]);
            g[jp] = pkmax0(a);
        }
    }
    // ---- ha2: 4 -> 1 (scalar head) ----
    const float* wha = P.w[HA2];
    float h_act = P.b[HA2][0];
    h_act = __builtin_fmaf(g[0].x, wha[0], h_act);
    h_act = __builtin_fmaf(g[0].y, wha[1], h_act);
    h_act = __builtin_fmaf(g[1].x, wha[2], h_act);
    h_act = __builtin_fmaf(g[1].y, wha[3], h_act);

    // ---- ka1: [k, kd, h_down(4)] -> 4 (2 jp) ----
    v2f q[2];
    {
        const u64* wp = reinterpret_cast<const u64*>(P.w[KA1]);
#pragma unroll
        for (int jp = 0; jp < 2; ++jp) {
            v2f a = bias2(P.b[KA1], jp);
            fmaH(a, xp23,  wp[0*2+jp]);    // k
            fmaH(a, xp89,  wp[1*2+jp]);    // kd
            fmaL(a, d2[0], wp[2*2+jp]);
            fmaH(a, d2[0], wp[3*2+jp]);
            fmaL(a, d2[1], wp[4*2+jp]);
            fmaH(a, d2[1], wp[5*2+jp]);
            q[jp] = pkmax0(a);
        }
    }
    // ---- ka2: 4 -> 1 ----
    const float* wka = P.w[KA2];
    float k_act = P.b[KA2][0];
    k_act = __builtin_fmaf(q[0].x, wka[0], k_act);
    k_act = __builtin_fmaf(q[0].y, wka[1], k_act);
    k_act = __builtin_fmaf(q[1].x, wka[2], k_act);
    k_act = __builtin_fmaf(q[1].y, wka[3], k_act);

    // ---- fa1: [f, fd, k_down(2)] -> 4 (2 jp) ----
    v2f r[2];
    {
        const u64* wp = reinterpret_cast<const u64*>(P.w[FA1]);
#pragma unroll
        for (int jp = 0; jp < 2; ++jp) {
            v2f a = bias2(P.b[FA1], jp);
            fmaL(a, xp45, wp[0*2+jp]);     // f
            fmaL(a, xpA,  wp[1*2+jp]);     // fd
            fmaL(a, e2,   wp[2*2+jp]);
            fmaH(a, e2,   wp[3*2+jp]);
            r[jp] = pkmax0(a);
        }
    }
    // ---- fa2: 4 -> 1 ----
    const float* wfa = P.w[FA2];
    float f_act = P.b[FA2][0];
    f_act = __builtin_fmaf(r[0].x, wfa[0], f_act);
    f_act = __builtin_fmaf(r[0].y, wfa[1], f_act);
    f_act = __builtin_fmaf(r[1].x, wfa[2], f_act);
    f_act = __builtin_fmaf(r[1].y, wfa[3], f_act);

    // ---- store ----
    float* po = out + row * 3;
    po[0] = h_act;
    po[1] = f_act;
    po[2] = k_act;
}

extern "C" void kernel_launch(void* const* d_in, const int* in_sizes, int n_in,
                              void* d_out, int out_size, void* d_ws, size_t ws_size,
                              hipStream_t stream) {
    const float* x = (const float*)d_in[0];
    float* out = (float*)d_out;
    const int B = in_sizes[0] / 11;

    WPtrs P;
    for (int i = 0; i < 19; ++i) {
        P.w[i] = (const float*)d_in[1 + 2*i];
        P.b[i] = (const float*)d_in[2 + 2*i];
    }

    const int blocks = (int)(((long long)B + BLOCK - 1) / BLOCK);
    pnet_kernel<<<blocks, BLOCK, 0, stream>>>(x, out, B, P);
}